// Round 4
// baseline (8370.089 us; speedup 1.0000x reference)
//
#include <hip/hip_runtime.h>
#include <hip/hip_cooperative_groups.h>

namespace cg = cooperative_groups;

#define IDX_BITS 20
#define IDX_MASK ((1u << IDX_BITS) - 1)
#define NTHREADS 256
#define MAX_GRID 2048
#define MAXPASS 500
#define SC_CAP 256

typedef unsigned long long u64;

// Per-edge comparisons are always intra-segment (kNN rows are segment-local),
// so the comparison key drops seg: key = (~float_bits(hier) << 20) | v.
// Smaller = earlier in the reference's processing order (desc hier, asc index).
__device__ __forceinline__ u64 pack_key(float h, int v) {
  unsigned bits = __float_as_uint(h);
  return ((u64)(~bits) << IDX_BITS) | (unsigned)v;
}

struct Ctx {
  const int* __restrict__ neighs;
  const float* __restrict__ hier;
  const int* __restrict__ row_splits;
  int V, K, nseg;
  u64* assign;       // [V] min grabber key; ~0 = alive. Centre self-grab -> assign==own key.
  int* tagA;         // [V] ping-pong "blocked at pass p" tags (plain racy stores of p)
  int* tagB;
  u64* centre_key;   // [V] full key incl. seg (for global ranking)
  int* centre_v;     // [V]
  int* rank_of;      // [V]
  int* cnt;          // [0..2] survivor flags mod 3, [3] centre count, [8+s] seg counts
  int* out_sel;
  int* out_rs;
  int* out_gg;
};

__global__ void __launch_bounds__(NTHREADS, 8) cluster_kernel(Ctx c) {
  cg::grid_group grid = cg::this_grid();
  const int tid = blockIdx.x * blockDim.x + threadIdx.x;
  const int nthr = gridDim.x * blockDim.x;
  const int W = nthr >> 6;          // total waves
  const int gw = tid >> 6;          // global wave id
  const int lane = threadIdx.x & 63;
  const int V = c.V, K = c.K;

  __shared__ int sc_cnt;
  __shared__ int sc_base;
  __shared__ int sc_list[SC_CAP];
  __shared__ u64 shp[NTHREADS];

  if (threadIdx.x == 0) sc_cnt = 0;

  // ---------- fused decide+block passes: ONE grid.sync per pass ----------
  // Pass p: live u is a centre iff rb_tag[u] != p-1 (nobody live+earlier tagged
  // it last pass). Survivors tag later out-neighbours into wb with value p.
  // Tag stores are plain (racy identical values) -> stay in L2, no coherent RMW.
  // A centre deciding at pass p tagged its victims at p-1 (it was a survivor
  // then), so no same-pass decide-vs-kill race. Same-pass-grabbed survivors
  // act one extra pass and are filtered by the assign test next pass.
  int p = 0;
  while (true) {
    int* rb = (p & 1) ? c.tagA : c.tagB;   // written at pass p-1
    int* wb = (p & 1) ? c.tagB : c.tagA;   // written at pass p
    bool any_surv = false;

    for (int u = gw; u < V; u += W) {
      u64 y = c.assign[u];                 // broadcast 8B load
      float hu = c.hier[u];
      u64 pu = pack_key(hu, u);
      if (y <= pu) continue;               // dead, or decided centre (y == pu)
      bool centre = (p > 0) && (rb[u] != p - 1);
      const int* row = c.neighs + (size_t)u * K;
      if (centre) {
        // grab all later out-neighbours + self. Only ~nC*K atomics total.
        for (int j = lane; j < K; j += 64)
          atomicMin(&c.assign[row[j]], pu);
        if (lane == 0) {
          int s = atomicAdd(&sc_cnt, 1);
          if (s < SC_CAP) sc_list[s] = u;
          else {                           // overflow fallback
            int slot = atomicAdd(&c.cnt[3], 1);
            int seg = 0;
            for (int t = 1; t < c.nseg; ++t) seg += (u >= c.row_splits[t]);
            c.centre_v[slot] = u;
            c.centre_key[slot] = ((u64)seg << 52) | pu;
            atomicAdd(&c.cnt[8 + seg], 1);
          }
        }
      } else {
        any_surv = true;
        for (int j = lane; j < K; j += 64) {
          int w = row[j];
          u64 pw = pack_key(c.hier[w], w);  // 4B cached gather
          if (pw > pu) wb[w] = p;           // plain racy same-value store
        }
      }
    }
    if (any_surv && lane == 0) c.cnt[p % 3] = 1;
    if (tid == 0) c.cnt[(p + 1) % 3] = 0;   // pre-zero next pass's flag (mod 3: no reuse race)

    // flush block-local centre staging (1 global atomicAdd per block per pass)
    __syncthreads();
    int nloc = min(sc_cnt, SC_CAP);
    if (threadIdx.x == 0 && nloc > 0) sc_base = atomicAdd(&c.cnt[3], nloc);
    __syncthreads();
    for (int i = threadIdx.x; i < nloc; i += NTHREADS) {
      int v = sc_list[i];
      int seg = 0;
      for (int t = 1; t < c.nseg; ++t) seg += (v >= c.row_splits[t]);
      c.centre_v[sc_base + i] = v;
      c.centre_key[sc_base + i] = ((u64)seg << 52) | pack_key(c.hier[v], v);
      atomicAdd(&c.cnt[8 + seg], 1);
    }
    __syncthreads();
    if (threadIdx.x == 0) sc_cnt = 0;

    __threadfence();
    grid.sync();
    int flag = c.cnt[p % 3];
    ++p;
    if (!flag || p > MAXPASS) break;
  }

  // ---------- centre ranks: O(nC^2) LDS-tiled counting (nC ~ thousands) ----------
  int nC = c.cnt[3];
  {
    bool have = tid < nC;
    u64 mykey = have ? c.centre_key[tid] : 0;
    int myv = have ? c.centre_v[tid] : 0;
    int myrank = 0;
    for (int cs = 0; cs < nC; cs += NTHREADS) {
      int j = cs + threadIdx.x;
      shp[threadIdx.x] = (j < nC) ? c.centre_key[j] : ~0ull;
      __syncthreads();
      int lim = min(NTHREADS, nC - cs);
      for (int t = 0; t < lim; ++t) myrank += (shp[t] < mykey) ? 1 : 0;
      __syncthreads();
    }
    if (have) {
      c.out_sel[myrank] = myv;   // rank among centre keys == cumsum position
      c.rank_of[myv] = myrank;
    }
  }
  if (tid == 0) {
    int run = 0;
    c.out_rs[0] = 0;
    for (int s = 0; s < c.nseg; ++s) { run += c.cnt[8 + s]; c.out_rs[s + 1] = run; }
  }
  __threadfence();
  grid.sync();

  // ---------- ggather ----------
  for (int v = tid; v < V; v += nthr) {
    u64 y = c.assign[v];
    u64 pv = pack_key(c.hier[v], v);
    int ctr = (y <= pv) ? (int)(y & IDX_MASK) : v;  // centre self-grab -> y==pv -> ctr=v
    c.out_gg[v] = c.rank_of[ctr];
  }
}

extern "C" void kernel_launch(void* const* d_in, const int* in_sizes, int n_in,
                              void* d_out, int out_size, void* d_ws, size_t ws_size,
                              hipStream_t stream) {
  Ctx c;
  c.neighs = (const int*)d_in[0];
  c.hier = (const float*)d_in[1];
  c.row_splits = (const int*)d_in[2];
  c.V = in_sizes[1];
  c.K = in_sizes[0] / c.V;
  c.nseg = in_sizes[2] - 1;

  char* pm = (char*)d_ws;
  const size_t V = (size_t)c.V;
  c.assign = (u64*)pm;        pm += V * 8;
  c.tagA = (int*)pm;          pm += V * 4;
  c.tagB = (int*)pm;          pm += V * 4;
  size_t ff_bytes = V * 16;   // assign + tagA + tagB -> 0xFF
  c.centre_key = (u64*)pm;    pm += V * 8;
  c.centre_v = (int*)pm;      pm += V * 4;
  c.rank_of = (int*)pm;       pm += V * 4;
  c.cnt = (int*)pm;           pm += 64 * 4;

  int* out = (int*)d_out;
  c.out_sel = out;
  c.out_rs = out + c.V;
  c.out_gg = out + c.V + c.nseg + 1;

  hipMemsetAsync(d_ws, 0xFF, ff_bytes, stream);
  hipMemsetAsync((void*)c.cnt, 0, 64 * 4, stream);
  hipMemsetAsync((void*)c.out_sel, 0xFF, V * 4, stream);

  // grid = full co-residency (8 blocks/CU target via __launch_bounds__(256,8))
  int dev = 0, nCU = 0, maxB = 0;
  hipGetDevice(&dev);
  hipDeviceGetAttribute(&nCU, hipDeviceAttributeMultiprocessorCount, dev);
  hipOccupancyMaxActiveBlocksPerMultiprocessor(&maxB, cluster_kernel, NTHREADS, 0);
  if (nCU <= 0) nCU = 256;
  if (maxB <= 0) maxB = 4;
  int grid = nCU * maxB;
  if (grid > MAX_GRID) grid = MAX_GRID;

  void* args[] = { &c };
  hipLaunchCooperativeKernel((void*)cluster_kernel, dim3(grid), dim3(NTHREADS),
                             args, 0, stream);
}

// Round 5
// 3777.864 us; speedup vs baseline: 2.2156x; 2.2156x over previous
//
#include <hip/hip_runtime.h>
#include <hip/hip_cooperative_groups.h>

namespace cg = cooperative_groups;

#define IDX_BITS 20
#define IDX_MASK ((1u << IDX_BITS) - 1)
#define NTHREADS 1024
#define MAX_GRID 512
#define TAIL_T 8192
#define GRID_ROUND_CAP 64
#define TAIL_ROUND_CAP 6000
#define SC_CAP 256
#define SV_CAP 1024

typedef unsigned long long u64;

// All edges are intra-segment, so the comparison key drops seg:
// key = (~float_bits(hier) << 20) | v ; smaller = earlier in processing order.
__device__ __forceinline__ u64 pack_key(float h, int v) {
  return ((u64)(~__float_as_uint(h)) << IDX_BITS) | (unsigned)v;
}

struct Ctx {
  const int* __restrict__ neighs;
  const float* __restrict__ hier;
  const int* __restrict__ row_splits;
  int V, K, nseg;
  u64* assign;       // [V] min grabber key; ~0 = alive; ==own key -> decided centre
  int* tag;          // [V] "blocked at round r" tags (plain racy stores of r)
  int* listA;        // [V] frontier ping
  int* listB;        // [V] frontier pong
  u64* centre_key;   // [V] full key incl. seg (for global ranking)
  int* centre_v;     // [V]
  int* rank_of;      // [V]
  int* cnt;          // [0,1] alive counters (round parity), [2] centre count, [8+s] seg counts
  int* out_sel;
  int* out_rs;
  int* out_gg;
};

__global__ void __launch_bounds__(NTHREADS, 8) cluster_kernel(Ctx c) {
  cg::grid_group grid = cg::this_grid();
  const int tid = blockIdx.x * blockDim.x + threadIdx.x;
  const int nthr = gridDim.x * blockDim.x;
  const int W = nthr >> 6;            // total waves
  const int gw = tid >> 6;            // global wave id
  const int lane = threadIdx.x & 63;
  const int bw = threadIdx.x >> 6;    // block-local wave id
  const int NBW = blockDim.x >> 6;    // waves per block
  const int V = c.V, K = c.K;

  __shared__ int sc_cnt, sv_cnt, sv_base;
  __shared__ int sc_list[SC_CAP];
  __shared__ int sv_list[SV_CAP];
  __shared__ u64 shp[NTHREADS];

  auto record_centre = [&](int v, u64 pv) {
    int slot = atomicAdd(&c.cnt[2], 1);
    int seg = 0;
    for (int t = 1; t < c.nseg; ++t) seg += (v >= c.row_splits[t]);
    c.centre_v[slot] = v;
    c.centre_key[slot] = ((u64)seg << 52) | pv;   // ~bits occupies [20,52) -> no overlap
    atomicAdd(&c.cnt[8 + seg], 1);
  };

  // ================= grid phase: 2-phase rounds, frontier-compacted =================
  // Round r: phase B = live u tags later out-neighbours with r; sync;
  // phase C = live u with tag[u]!=r is a centre (all earlier in-neighbours dead),
  // grabs via inert-late atomicMin; survivors compact into next list.
  // Kills decided in C are visible in B of r+1 -> one dependency level per round.
  int aliveN = V, r = 0;
  while (true) {
    const int* rl = (r & 1) ? c.listA : c.listB;
    int* wl = (r & 1) ? c.listB : c.listA;
    if (tid == 0) c.cnt[(r + 1) & 1] = 0;          // safe: 2 syncs since last read
    if (threadIdx.x == 0) { sc_cnt = 0; sv_cnt = 0; }

    // phase B
    for (int i = gw; i < aliveN; i += W) {
      int u = r ? rl[i] : i;                       // round 0: implicit identity list
      u64 pu = pack_key(c.hier[u], u);
      if (c.assign[u] <= pu) continue;             // dead or decided
      const int* row = c.neighs + (size_t)u * K;
      for (int j = lane; j < K; j += 64) {
        int w = row[j];
        if (pack_key(c.hier[w], w) > pu) c.tag[w] = r;   // racy same-value store
      }
    }
    __threadfence();
    grid.sync();

    // phase C
    for (int i = gw; i < aliveN; i += W) {
      int u = r ? rl[i] : i;
      u64 pu = pack_key(c.hier[u], u);
      if (c.assign[u] <= pu) continue;
      if (c.tag[u] != r) {
        const int* row = c.neighs + (size_t)u * K;
        for (int j = lane; j < K; j += 64)
          atomicMin(&c.assign[row[j]], pu);        // incl. self: marks centre decided
        if (lane == 0) {
          int s = atomicAdd(&sc_cnt, 1);
          if (s < SC_CAP) sc_list[s] = u; else record_centre(u, pu);
        }
      } else if (lane == 0) {
        int s = atomicAdd(&sv_cnt, 1);
        if (s < SV_CAP) sv_list[s] = u;
        else { int g = atomicAdd(&c.cnt[(r + 1) & 1], 1); wl[g] = u; }
      }
    }
    __syncthreads();
    int nsc = min(sc_cnt, SC_CAP), nsv = min(sv_cnt, SV_CAP);
    if (threadIdx.x == 0 && nsv) sv_base = atomicAdd(&c.cnt[(r + 1) & 1], nsv);
    __syncthreads();
    for (int i = threadIdx.x; i < nsv; i += blockDim.x) wl[sv_base + i] = sv_list[i];
    for (int i = threadIdx.x; i < nsc; i += blockDim.x) {
      int v = sc_list[i];
      record_centre(v, pack_key(c.hier[v], v));
    }
    __threadfence();
    grid.sync();
    aliveN = c.cnt[(r + 1) & 1];
    ++r;
    if (aliveN == 0 || aliveN <= TAIL_T || r >= GRID_ROUND_CAP) break;
  }

  // ================= tail phase: single block, cheap barriers =================
  // Remaining ~100 dependency levels carry little work; run them in block 0 with
  // __threadfence (L1/L2 freshness after own atomics) + __syncthreads per phase.
  if (aliveN > 0 && blockIdx.x == 0) {
    int an = aliveN, tr = r;
    const int trCap = r + TAIL_ROUND_CAP;
    while (an > 0 && tr < trCap) {
      const int* trl = (tr & 1) ? c.listA : c.listB;
      int* twl = (tr & 1) ? c.listB : c.listA;
      for (int i = bw; i < an; i += NBW) {
        int u = trl[i];
        u64 pu = pack_key(c.hier[u], u);
        if (c.assign[u] <= pu) continue;
        const int* row = c.neighs + (size_t)u * K;
        for (int j = lane; j < K; j += 64) {
          int w = row[j];
          if (pack_key(c.hier[w], w) > pu) c.tag[w] = tr;
        }
      }
      __threadfence(); __syncthreads();
      if (threadIdx.x == 0) sv_cnt = 0;
      __syncthreads();
      for (int i = bw; i < an; i += NBW) {
        int u = trl[i];
        u64 pu = pack_key(c.hier[u], u);
        if (c.assign[u] <= pu) continue;
        if (c.tag[u] != tr) {
          const int* row = c.neighs + (size_t)u * K;
          for (int j = lane; j < K; j += 64)
            atomicMin(&c.assign[row[j]], pu);
          if (lane == 0) record_centre(u, pu);
        } else if (lane == 0) {
          int s = atomicAdd(&sv_cnt, 1);
          twl[s] = u;
        }
      }
      __threadfence(); __syncthreads();
      an = sv_cnt;
      ++tr;
    }
  }
  __threadfence();
  grid.sync();

  // ================= centre ranks: O(nC^2) LDS-tiled counting =================
  int nC = c.cnt[2];
  if ((long long)blockIdx.x * blockDim.x < (long long)nC) {   // uniform per block
    bool have = tid < nC;
    u64 mykey = have ? c.centre_key[tid] : 0;
    int myv = have ? c.centre_v[tid] : 0;
    int myrank = 0;
    for (int cs = 0; cs < nC; cs += NTHREADS) {
      int j = cs + threadIdx.x;
      shp[threadIdx.x] = (j < nC) ? c.centre_key[j] : ~0ull;
      __syncthreads();
      int lim = min(NTHREADS, nC - cs);
      for (int t = 0; t < lim; ++t) myrank += (shp[t] < mykey) ? 1 : 0;
      __syncthreads();
    }
    if (have) {
      c.out_sel[myrank] = myv;      // rank among centre keys == cumsum position
      c.rank_of[myv] = myrank;
    }
  }
  if (tid == 0) {
    int run = 0;
    c.out_rs[0] = 0;
    for (int s = 0; s < c.nseg; ++s) { run += c.cnt[8 + s]; c.out_rs[s + 1] = run; }
  }
  __threadfence();
  grid.sync();

  // ================= ggather =================
  for (int v = tid; v < V; v += nthr) {
    u64 y = c.assign[v];
    u64 pv = pack_key(c.hier[v], v);
    int ctr = (y < pv) ? (int)(y & IDX_MASK) : v;   // y==pv -> centre -> self
    c.out_gg[v] = c.rank_of[ctr];
  }
}

extern "C" void kernel_launch(void* const* d_in, const int* in_sizes, int n_in,
                              void* d_out, int out_size, void* d_ws, size_t ws_size,
                              hipStream_t stream) {
  Ctx c;
  c.neighs = (const int*)d_in[0];
  c.hier = (const float*)d_in[1];
  c.row_splits = (const int*)d_in[2];
  c.V = in_sizes[1];
  c.K = in_sizes[0] / c.V;
  c.nseg = in_sizes[2] - 1;

  char* pm = (char*)d_ws;
  const size_t V = (size_t)c.V;
  c.assign = (u64*)pm;        pm += V * 8;
  c.tag = (int*)pm;           pm += V * 4;
  size_t ff_bytes = V * 12;   // assign -> ~0 (alive), tag -> -1
  c.listA = (int*)pm;         pm += V * 4;
  c.listB = (int*)pm;         pm += V * 4;
  c.centre_key = (u64*)pm;    pm += V * 8;
  c.centre_v = (int*)pm;      pm += V * 4;
  c.rank_of = (int*)pm;       pm += V * 4;
  c.cnt = (int*)pm;           pm += 64 * 4;

  int* out = (int*)d_out;
  c.out_sel = out;
  c.out_rs = out + c.V;
  c.out_gg = out + c.V + c.nseg + 1;

  hipMemsetAsync(d_ws, 0xFF, ff_bytes, stream);
  hipMemsetAsync((void*)c.cnt, 0, 64 * 4, stream);
  hipMemsetAsync((void*)c.out_sel, 0xFF, V * 4, stream);

  int dev = 0, nCU = 0, maxB = 0;
  hipGetDevice(&dev);
  hipDeviceGetAttribute(&nCU, hipDeviceAttributeMultiprocessorCount, dev);
  hipOccupancyMaxActiveBlocksPerMultiprocessor(&maxB, cluster_kernel, NTHREADS, 0);
  if (nCU <= 0) nCU = 256;
  if (maxB <= 0) maxB = 1;
  int grid = nCU * maxB;
  if (grid > MAX_GRID) grid = MAX_GRID;

  void* args[] = { &c };
  hipLaunchCooperativeKernel((void*)cluster_kernel, dim3(grid), dim3(NTHREADS),
                             args, 0, stream);
}

// Round 6
// 2329.596 us; speedup vs baseline: 3.5929x; 1.6217x over previous
//
#include <hip/hip_runtime.h>
#include <hip/hip_cooperative_groups.h>

namespace cg = cooperative_groups;

#define IDX_BITS 20
#define IDX_MASK ((1u << IDX_BITS) - 1)
#define NTHREADS 1024
#define MAX_GRID 512
#define TAIL_T 16384
#define TAIL_BLOCKS 16
#define GRID_ROUND_CAP 32
#define MAX_ROUNDS 4000
#define SC_CAP 512
#define SV_CAP 2048

typedef unsigned long long u64;

// All edges are intra-segment, so the per-edge comparison key drops seg:
// key = (~float_bits(hier) << 20) | v ; smaller = earlier in processing order.
__device__ __forceinline__ u64 pack_key(float h, int v) {
  return ((u64)(~__float_as_uint(h)) << IDX_BITS) | (unsigned)v;
}

struct Ctx {
  const int* __restrict__ neighs;
  const float* __restrict__ hier;
  const int* __restrict__ row_splits;
  int V, K, nseg;
  u64* assign;       // [V] min grabber key; ~0 = alive; == own key -> decided centre
  int* tag;          // [V] "blocked at round r" tags (plain racy stores of r)
  int* listA;        // [V] frontier ping
  int* listB;        // [V] frontier pong
  u64* centre_key;   // [V] full key incl. seg (for global ranking)
  int* centre_v;     // [V]
  int* rank_of;      // [V]
  int* cnt;          // [0,1] survivor counters (parity), [2] nC, [3] xbar, [4] claim, [8+s] seg
  int* out_sel;
  int* out_rs;
  int* out_gg;
};

// Monotonic arrive-counter barrier for the TAIL_BLOCKS group. No reset, no
// sense reversal; target = TAIL_BLOCKS * episode. threadfence on both sides
// (L1 invalidate) preserves the cross-round freshness argument.
__device__ __forceinline__ void xbar(int* bar, int target) {
  __syncthreads();
  __threadfence();
  if (threadIdx.x == 0) {
    __hip_atomic_fetch_add(bar, 1, __ATOMIC_RELEASE, __HIP_MEMORY_SCOPE_AGENT);
    while (__hip_atomic_load(bar, __ATOMIC_ACQUIRE, __HIP_MEMORY_SCOPE_AGENT) < target)
      __builtin_amdgcn_s_sleep(2);
  }
  __syncthreads();
  __threadfence();
}

__global__ void __launch_bounds__(NTHREADS, 8) cluster_kernel(Ctx c) {
  cg::grid_group grid = cg::this_grid();
  const int tid = blockIdx.x * blockDim.x + threadIdx.x;
  const int nthr = gridDim.x * blockDim.x;
  const int W = nthr >> 6;
  const int gw = tid >> 6;
  const int lane = threadIdx.x & 63;
  const int bw = threadIdx.x >> 6;
  const int NBW = blockDim.x >> 6;
  const int V = c.V, K = c.K;

  __shared__ int sc_cnt, sv_cnt, sc_base, sv_base, claim_sh;
  __shared__ int seg_hist[8];
  __shared__ int sc_list[SC_CAP];
  __shared__ int sv_list[SV_CAP];
  __shared__ u64 shp[NTHREADS];

  auto record_direct = [&](int v, u64 pv) {   // SC_CAP overflow fallback (rare)
    int slot = atomicAdd(&c.cnt[2], 1);
    int seg = 0;
    for (int t = 1; t < c.nseg; ++t) seg += (v >= c.row_splits[t]);
    c.centre_v[slot] = v;
    c.centre_key[slot] = ((u64)seg << 52) | pv;
    atomicAdd(&c.cnt[8 + seg], 1);
  };
  // Block-aggregated flush: ONE global atomicAdd for slots + <=nseg for counts.
  auto flush_block = [&](int* wl, int* surv_counter) {
    __syncthreads();
    int nsc = min(sc_cnt, SC_CAP), nsv = min(sv_cnt, SV_CAP);
    if (threadIdx.x == 0 && nsc) sc_base = atomicAdd(&c.cnt[2], nsc);
    if (threadIdx.x == 0 && nsv) sv_base = atomicAdd(surv_counter, nsv);
    if (threadIdx.x < 8) seg_hist[threadIdx.x] = 0;
    __syncthreads();
    for (int i = threadIdx.x; i < nsv; i += blockDim.x) wl[sv_base + i] = sv_list[i];
    for (int i = threadIdx.x; i < nsc; i += blockDim.x) {
      int v = sc_list[i];
      int seg = 0;
      for (int t = 1; t < c.nseg; ++t) seg += (v >= c.row_splits[t]);
      c.centre_v[sc_base + i] = v;
      c.centre_key[sc_base + i] = ((u64)seg << 52) | pack_key(c.hier[v], v);
      atomicAdd(&seg_hist[seg], 1);
    }
    __syncthreads();
    if (threadIdx.x < c.nseg) {
      int h = seg_hist[threadIdx.x];
      if (h) atomicAdd(&c.cnt[8 + threadIdx.x], h);
    }
    __syncthreads();
    if (threadIdx.x == 0) { sc_cnt = 0; sv_cnt = 0; }
  };

  if (threadIdx.x == 0) { sc_cnt = 0; sv_cnt = 0; }

  // ================= grid phase: 2-phase rounds, full grid =================
  // Round r: phase B = live u tags later out-neighbours with r; sync;
  // phase C = live u with tag[u]!=r is a centre (all earlier in-neighbours
  // dead); grabs via unguarded atomicMin (values > target's own key are inert
  // for every consumer); survivors compact. One dependency level per round.
  int aliveN = V, r = 0;
  while (true) {
    const int* rl = (r & 1) ? c.listA : c.listB;
    int* wl = (r & 1) ? c.listB : c.listA;
    if (tid == 0) c.cnt[(r + 1) & 1] = 0;     // 2 syncs since last read of slot

    // phase B
    for (int i = gw; i < aliveN; i += W) {
      int u = r ? rl[i] : i;
      u64 pu = pack_key(c.hier[u], u);
      if (c.assign[u] <= pu) continue;
      const int* row = c.neighs + (size_t)u * K;
      for (int j = lane; j < K; j += 64) {
        int w = row[j];
        if (pack_key(c.hier[w], w) > pu) c.tag[w] = r;
      }
    }
    __threadfence();
    grid.sync();

    // phase C
    for (int i = gw; i < aliveN; i += W) {
      int u = r ? rl[i] : i;
      u64 pu = pack_key(c.hier[u], u);
      if (c.assign[u] <= pu) continue;
      if (c.tag[u] != r) {
        const int* row = c.neighs + (size_t)u * K;
        for (int j = lane; j < K; j += 64)
          atomicMin(&c.assign[row[j]], pu);   // incl. self: marks centre decided
        if (lane == 0) {
          int s = atomicAdd(&sc_cnt, 1);
          if (s < SC_CAP) sc_list[s] = u; else record_direct(u, pu);
        }
      } else if (lane == 0) {
        // fresh (agent-scope) re-check to cut stale listings of same-round grabs
        u64 y = __hip_atomic_load(&c.assign[u], __ATOMIC_RELAXED, __HIP_MEMORY_SCOPE_AGENT);
        if (y > pu) {
          int s = atomicAdd(&sv_cnt, 1);
          if (s < SV_CAP) sv_list[s] = u;
          else { int g = atomicAdd(&c.cnt[(r + 1) & 1], 1); wl[g] = u; }
        }
      }
    }
    flush_block(wl, &c.cnt[(r + 1) & 1]);
    __threadfence();
    grid.sync();
    aliveN = c.cnt[(r + 1) & 1];
    ++r;
    if (aliveN == 0 || aliveN <= TAIL_T || r >= GRID_ROUND_CAP) break;
  }

  // ================= tail: same rounds on TAIL_BLOCKS blocks + spin barrier ====
  if (aliveN > 0) {
    if (threadIdx.x == 0) claim_sh = atomicAdd(&c.cnt[4], 1);
    __syncthreads();
    int trank = claim_sh;
    if (trank < TAIL_BLOCKS) {
      const int Wt = TAIL_BLOCKS * NBW;
      const int tw = trank * NBW + bw;
      int an = aliveN, tr = r, ep = 0;
      while (true) {
        const int* rl = (tr & 1) ? c.listA : c.listB;
        int* wl = (tr & 1) ? c.listB : c.listA;
        if (trank == 0 && threadIdx.x == 0) c.cnt[(tr + 1) & 1] = 0;

        for (int i = tw; i < an; i += Wt) {           // phase B
          int u = rl[i];
          u64 pu = pack_key(c.hier[u], u);
          if (c.assign[u] <= pu) continue;
          const int* row = c.neighs + (size_t)u * K;
          for (int j = lane; j < K; j += 64) {
            int w = row[j];
            if (pack_key(c.hier[w], w) > pu) c.tag[w] = tr;
          }
        }
        xbar(&c.cnt[3], TAIL_BLOCKS * (++ep));

        for (int i = tw; i < an; i += Wt) {           // phase C
          int u = rl[i];
          u64 pu = pack_key(c.hier[u], u);
          if (c.assign[u] <= pu) continue;
          if (c.tag[u] != tr) {
            const int* row = c.neighs + (size_t)u * K;
            for (int j = lane; j < K; j += 64)
              atomicMin(&c.assign[row[j]], pu);
            if (lane == 0) {
              int s = atomicAdd(&sc_cnt, 1);
              if (s < SC_CAP) sc_list[s] = u; else record_direct(u, pu);
            }
          } else if (lane == 0) {
            u64 y = __hip_atomic_load(&c.assign[u], __ATOMIC_RELAXED, __HIP_MEMORY_SCOPE_AGENT);
            if (y > pu) {
              int s = atomicAdd(&sv_cnt, 1);
              if (s < SV_CAP) sv_list[s] = u;
              else { int g = atomicAdd(&c.cnt[(tr + 1) & 1], 1); wl[g] = u; }
            }
          }
        }
        flush_block(wl, &c.cnt[(tr + 1) & 1]);
        xbar(&c.cnt[3], TAIL_BLOCKS * (++ep));
        an = c.cnt[(tr + 1) & 1];
        ++tr;
        if (an == 0 || tr >= MAX_ROUNDS) break;
      }
    }
  }
  __threadfence();
  grid.sync();

  // ================= centre ranks: O(nC^2) LDS-tiled counting =================
  int nC = c.cnt[2];
  if ((long long)blockIdx.x * blockDim.x < (long long)nC) {
    bool have = tid < nC;
    u64 mykey = have ? c.centre_key[tid] : 0;
    int myv = have ? c.centre_v[tid] : 0;
    int myrank = 0;
    for (int cs = 0; cs < nC; cs += NTHREADS) {
      int j = cs + threadIdx.x;
      shp[threadIdx.x] = (j < nC) ? c.centre_key[j] : ~0ull;
      __syncthreads();
      int lim = min(NTHREADS, nC - cs);
      for (int t = 0; t < lim; ++t) myrank += (shp[t] < mykey) ? 1 : 0;
      __syncthreads();
    }
    if (have) {
      c.out_sel[myrank] = myv;     // rank among centre keys == cumsum position
      c.rank_of[myv] = myrank;
    }
  }
  if (tid == 0) {
    int run = 0;
    c.out_rs[0] = 0;
    for (int s = 0; s < c.nseg; ++s) { run += c.cnt[8 + s]; c.out_rs[s + 1] = run; }
  }
  __threadfence();
  grid.sync();

  // ================= ggather =================
  for (int v = tid; v < V; v += nthr) {
    u64 y = c.assign[v];
    u64 pv = pack_key(c.hier[v], v);
    int ctr = (y < pv) ? (int)(y & IDX_MASK) : v;   // y==pv -> centre -> self
    c.out_gg[v] = c.rank_of[ctr];
  }
}

extern "C" void kernel_launch(void* const* d_in, const int* in_sizes, int n_in,
                              void* d_out, int out_size, void* d_ws, size_t ws_size,
                              hipStream_t stream) {
  Ctx c;
  c.neighs = (const int*)d_in[0];
  c.hier = (const float*)d_in[1];
  c.row_splits = (const int*)d_in[2];
  c.V = in_sizes[1];
  c.K = in_sizes[0] / c.V;
  c.nseg = in_sizes[2] - 1;

  char* pm = (char*)d_ws;
  const size_t V = (size_t)c.V;
  c.assign = (u64*)pm;        pm += V * 8;
  c.tag = (int*)pm;           pm += V * 4;
  size_t ff_bytes = V * 12;   // assign -> ~0 (alive), tag -> -1
  c.listA = (int*)pm;         pm += V * 4;
  c.listB = (int*)pm;         pm += V * 4;
  c.centre_key = (u64*)pm;    pm += V * 8;
  c.centre_v = (int*)pm;      pm += V * 4;
  c.rank_of = (int*)pm;       pm += V * 4;
  c.cnt = (int*)pm;           pm += 64 * 4;

  int* out = (int*)d_out;
  c.out_sel = out;
  c.out_rs = out + c.V;
  c.out_gg = out + c.V + c.nseg + 1;

  hipMemsetAsync(d_ws, 0xFF, ff_bytes, stream);
  hipMemsetAsync((void*)c.cnt, 0, 64 * 4, stream);
  hipMemsetAsync((void*)c.out_sel, 0xFF, V * 4, stream);

  int dev = 0, nCU = 0, maxB = 0;
  hipGetDevice(&dev);
  hipDeviceGetAttribute(&nCU, hipDeviceAttributeMultiprocessorCount, dev);
  hipOccupancyMaxActiveBlocksPerMultiprocessor(&maxB, cluster_kernel, NTHREADS, 0);
  if (nCU <= 0) nCU = 256;
  if (maxB <= 0) maxB = 1;
  int grid = nCU * maxB;
  if (grid > MAX_GRID) grid = MAX_GRID;

  void* args[] = { &c };
  hipLaunchCooperativeKernel((void*)cluster_kernel, dim3(grid), dim3(NTHREADS),
                             args, 0, stream);
}